// Round 2
// baseline (490.195 us; speedup 1.0000x reference)
//
#include <hip/hip_runtime.h>
#include <stdint.h>

#define ROWLEN 8192
#define KSEL 64
#define NT 256
#define VPT 8      // float4 per thread -> 32 elements per thread
#define NH 8       // round-1 histogram copies (wave * lane-parity)
#define HPAD 264   // 256 bins + 8 skew so copies land on different banks
#define MAXEQ 256

// Order-preserving f32 -> u32 key: larger float <=> larger key (total order).
__device__ __forceinline__ uint32_t f2key(float f) {
    uint32_t u = __float_as_uint(f);
    return (u & 0x80000000u) ? ~u : (u | 0x80000000u);
}
// inverse of f2key
__device__ __forceinline__ float key2f(uint32_t k) {
    uint32_t u = (k & 0x80000000u) ? (k ^ 0x80000000u) : ~k;
    return __uint_as_float(u);
}

struct SelOut { uint32_t bin, k, cnt; };

// Thread t owns bin t (ascending). Finds bin holding the kcur-th largest
// (descending bin order) given total S. Returns bin, rank-in-bin, bin count.
__device__ __forceinline__ SelOut select256(uint32_t cnt, uint32_t S, uint32_t kcur,
                                            uint32_t* wsum, uint32_t* bc,
                                            int tid, int lane, int wid) {
    uint32_t p = cnt;                       // wave-inclusive scan
    #pragma unroll
    for (int d = 1; d < 64; d <<= 1) {
        uint32_t y = __shfl_up(p, (unsigned)d, 64);
        if (lane >= d) p += y;
    }
    if (lane == 63) wsum[wid] = p;
    __syncthreads();
    uint32_t off = 0;
    #pragma unroll
    for (int w = 0; w < 4; ++w) if (w < wid) off += wsum[w];
    p += off;                               // block-inclusive prefix
    uint32_t target = S - kcur + 1u;        // ascending-prefix crossing
    if (p >= target && (p - cnt) < target) {  // unique thread (cnt>=1 here)
        bc[0] = (uint32_t)tid;
        bc[1] = kcur - (S - p);             // rank within bin, in [1, cnt]
        bc[2] = cnt;
    }
    __syncthreads();
    SelOut o; o.bin = bc[0]; o.k = bc[1]; o.cnt = bc[2];
    return o;
}

extern "C" __global__ void __launch_bounds__(NT, 4)
topk_mask_kernel(const float* __restrict__ x, const float* __restrict__ w,
                 float* __restrict__ out) {
    __shared__ uint32_t hist8[NH][HPAD];    // 8448 B
    __shared__ uint32_t hist[256];          // rounds 2-4
    __shared__ uint32_t wsum[4];
    __shared__ uint32_t bc[3];
    __shared__ uint32_t eqidx[MAXEQ];       // indices of threshold-equal elems
    __shared__ uint32_t s_ec;
    __shared__ int s_cut;

    const int tid  = threadIdx.x;
    const int lane = tid & 63;
    const int wid  = tid >> 6;
    const int hcopy = (wid << 1) | (lane & 1);
    const size_t row = blockIdx.x;

    const float4* xr = (const float4*)(x + row * (size_t)ROWLEN);
    const float4* wr = (const float4*)w;

    // ---- load row (coalesced 16B/lane), form products, keep KEYS in regs ----
    uint32_t key[VPT][4];
    #pragma unroll
    for (int j = 0; j < VPT; ++j) {
        float4 a = xr[j * NT + tid];
        float4 b = wr[j * NT + tid];
        key[j][0] = f2key(a.x * b.x);
        key[j][1] = f2key(a.y * b.y);
        key[j][2] = f2key(a.z * b.z);
        key[j][3] = f2key(a.w * b.w);
    }

    // ---- round-1 histogram over top byte (8 skewed copies) ----
    for (int i = tid; i < NH * HPAD; i += NT) ((uint32_t*)hist8)[i] = 0;
    __syncthreads();
    #pragma unroll
    for (int j = 0; j < VPT; ++j)
        #pragma unroll
        for (int c = 0; c < 4; ++c)
            atomicAdd(&hist8[hcopy][key[j][c] >> 24], 1u);
    __syncthreads();

    // ---- two selection passes: 0 = top-64 (key), 1 = bottom-64 (~key) ----
    uint32_t Tkey[2];
    int cutv[2];

    for (int pass = 0; pass < 2; ++pass) {
        // round 1: transformed top byte of ~key is 255 - top byte of key
        uint32_t mb = pass ? (255u - (uint32_t)tid) : (uint32_t)tid;
        uint32_t cnt = 0;
        #pragma unroll
        for (int h = 0; h < NH; ++h) cnt += hist8[h][mb];
        SelOut s = select256(cnt, ROWLEN, KSEL, wsum, bc, tid, lane, wid);
        uint32_t prefix = s.bin << 24;
        uint32_t kcur = s.k, S = s.cnt;

        // rounds 2..4: histogram prefix-matching elements from registers
        for (int shift = 16; shift >= 0; shift -= 8) {
            hist[tid] = 0;
            __syncthreads();
            #pragma unroll
            for (int j = 0; j < VPT; ++j)
                #pragma unroll
                for (int c = 0; c < 4; ++c) {
                    uint32_t tk = pass ? ~key[j][c] : key[j][c];
                    if (((tk ^ prefix) >> (shift + 8)) == 0u)
                        atomicAdd(&hist[(tk >> shift) & 0xFFu], 1u);
                }
            __syncthreads();
            s = select256(hist[tid], S, kcur, wsum, bc, tid, lane, wid);
            prefix |= s.bin << shift;
            kcur = s.k;
            S = s.cnt;
        }

        // ---- UNCONDITIONAL tie resolution (runs on every row/pass) ----
        // Collect indices of all elements whose transformed key == prefix,
        // then cut = index of the kcur-th lowest index among them.
        // kcur == S  => cut = max equal index => all equals zeroed. Same path.
        if (tid == 0) { s_ec = 0; s_cut = 0x7FFFFFFF; }
        __syncthreads();
        #pragma unroll
        for (int j = 0; j < VPT; ++j)
            #pragma unroll
            for (int c = 0; c < 4; ++c) {
                uint32_t tk = pass ? ~key[j][c] : key[j][c];
                if (tk == prefix) {
                    uint32_t pos = atomicAdd(&s_ec, 1u);
                    if (pos < MAXEQ) eqidx[pos] = (uint32_t)((j * NT + tid) * 4 + c);
                }
            }
        __syncthreads();
        uint32_t ec = s_ec;
        int cut;
        if (ec <= MAXEQ) {
            if ((uint32_t)tid < ec) {
                uint32_t my = eqidx[tid];
                uint32_t rank = 0;
                for (uint32_t j2 = 0; j2 < ec; ++j2)
                    rank += (eqidx[j2] < my) ? 1u : 0u;
                if (rank + 1u == kcur) s_cut = (int)my;   // unique writer
            }
            __syncthreads();
            cut = s_cut;
        } else {
            cut = 0x7FFFFFFF;   // >256 exact-equal values: impossible for this input
        }
        Tkey[pass] = prefix;
        cutv[pass] = cut;
        __syncthreads();
    }

    const uint32_t Thi = Tkey[0], Tlo = Tkey[1];
    const int cutHi = cutv[0], cutLo = cutv[1];

    // ---- masked output (coalesced 16B/lane stores) ----
    float4* orow = (float4*)(out + row * (size_t)ROWLEN);
    #pragma unroll
    for (int j = 0; j < VPT; ++j) {
        float f[4];
        #pragma unroll
        for (int c = 0; c < 4; ++c) {
            uint32_t kh = key[j][c];
            uint32_t kl = ~kh;
            int idx = (j * NT + tid) * 4 + c;
            bool z = (kh > Thi) || (kh == Thi && idx <= cutHi) ||
                     (kl > Tlo) || (kl == Tlo && idx <= cutLo);
            f[c] = z ? 0.0f : key2f(kh);
        }
        orow[j * NT + tid] = make_float4(f[0], f[1], f[2], f[3]);
    }
}

extern "C" void kernel_launch(void* const* d_in, const int* in_sizes, int n_in,
                              void* d_out, int out_size, void* d_ws, size_t ws_size,
                              hipStream_t stream) {
    const float* x = (const float*)d_in[0];
    const float* w = (const float*)d_in[1];
    // d_in[2] is k (scalar int) == 64, baked in as KSEL
    float* out = (float*)d_out;
    const int rows = out_size / ROWLEN;   // 8192
    topk_mask_kernel<<<dim3(rows), dim3(NT), 0, stream>>>(x, w, out);
}